// Round 5
// baseline (241.953 us; speedup 1.0000x reference)
//
#include <hip/hip_runtime.h>
#include <stdint.h>

#define B_SZ 4096
#define D_SZ 512
#define SHIFT 64.0f

typedef __attribute__((ext_vector_type(4))) float floatx4;
typedef __attribute__((ext_vector_type(2))) long lng2;
typedef unsigned char u8;
typedef unsigned int u32;

#define FP8MFMA(accv, av, bv)                                                          \
    accv = __builtin_amdgcn_mfma_f32_16x16x32_fp8_fp8(av, bv, accv, 0, 0, 0)

// ---- K1: fp32->fp8(e4m3) convert (K-interleaved layout) + per-row time,
//      fused: histogram (block 0), accumulator zeroing, entailment partials.
//      K-perm: within each 64B K-window, 8B group (h,c) -> slot c*2+h; applied
//      to BOTH operands => Grammian unchanged. ----
__global__ __launch_bounds__(256) void prep_kernel(
    const float* __restrict__ img, const float* __restrict__ dna,
    const float* __restrict__ txt, const float* __restrict__ curv_p,
    const int* __restrict__ labels, int* __restrict__ hist,
    u8* __restrict__ f8, float* __restrict__ times,
    float* __restrict__ zero_f, float* __restrict__ ent_partial) {
    __shared__ int lhist[512];
    __shared__ float red[4];
    int t = threadIdx.x;
    int gid = blockIdx.x * 256 + t;
    if (gid < 49155) zero_f[gid] = 0.0f;    // rsum/csum + ce_acc/ent_acc/done

    if (blockIdx.x == 0) {                  // label histogram, single block
        lhist[t] = 0; lhist[t + 256] = 0;
        __syncthreads();
        for (int n = t; n < B_SZ; n += 256) atomicAdd(&lhist[labels[n]], 1);
        __syncthreads();
        hist[t] = lhist[t]; hist[t + 256] = lhist[t + 256];
    }

    int wave = gid >> 6;  // 0..12287
    int lane = t & 63;
    const float* src = (wave < B_SZ) ? img : (wave < 2 * B_SZ) ? dna : txt;
    int row = wave & (B_SZ - 1);
    const float* p = src + row * D_SZ + lane * 8;
    float4 v0 = *(const float4*)(p);
    float4 v1 = *(const float4*)(p + 4);
    float ss = v0.x*v0.x + v0.y*v0.y + v0.z*v0.z + v0.w*v0.w
             + v1.x*v1.x + v1.y*v1.y + v1.z*v1.z + v1.w*v1.w;
    u32 w0 = __builtin_amdgcn_cvt_pk_fp8_f32(v0.x, v0.y, 0, false);
    w0 = __builtin_amdgcn_cvt_pk_fp8_f32(v0.z, v0.w, w0, true);
    u32 w1 = __builtin_amdgcn_cvt_pk_fp8_f32(v1.x, v1.y, 0, false);
    w1 = __builtin_amdgcn_cvt_pk_fp8_f32(v1.z, v1.w, w1, true);
    uint2 pk; pk.x = w0; pk.y = w1;
    // lane = 8B group: window lane>>3, half (lane>>2)&1, chunk lane&3
    int gperm = (lane & 56) | ((lane & 3) << 1) | ((lane >> 2) & 1);
    *(uint2*)(f8 + (size_t)wave * D_SZ + gperm * 8) = pk;

    bool isdna = (wave >= B_SZ) && (wave < 2 * B_SZ);
    float dot = 0.0f, ssy = 0.0f;
    if (isdna) {                            // matching image row for entailment
        const float* y = img + row * D_SZ + lane * 8;
        float4 y0 = *(const float4*)y, y1 = *(const float4*)(y + 4);
        dot = v0.x*y0.x + v0.y*y0.y + v0.z*y0.z + v0.w*y0.w
            + v1.x*y1.x + v1.y*y1.y + v1.z*y1.z + v1.w*y1.w;
        ssy = y0.x*y0.x + y0.y*y0.y + y0.z*y0.z + y0.w*y0.w
            + y1.x*y1.x + y1.y*y1.y + y1.z*y1.z + y1.w*y1.w;
    }
    #pragma unroll
    for (int m = 1; m < 64; m <<= 1) {
        ss += __shfl_xor(ss, m);
        if (isdna) { dot += __shfl_xor(dot, m); ssy += __shfl_xor(ssy, m); }
    }
    float curv = curv_p[0];
    float ep = 0.0f;
    if (lane == 0) {
        float xt = sqrtf(1.0f / curv + ss);
        times[wave] = xt;
        if (isdna) {
            float yt = sqrtf(1.0f / curv + ssy);
            float nx = sqrtf(ss);
            float c = curv * (dot - xt * yt);                      // <= -1
            float numer = yt + c * xt;
            float denom = nx * sqrtf(fmaxf(c * c - 1.0f, 0.0f));
            float ai = numer / (denom + 1e-8f);
            ai = fminf(fmaxf(ai, -1.0f + 1e-8f), 1.0f - 1e-8f);
            float ang = acosf(ai);
            float as_in = 0.2f / (nx * sqrtf(curv) + 1e-6f);       // 2*min_radius
            as_in = fminf(fmaxf(as_in, -1.0f + 1e-6f), 1.0f - 1e-6f);
            float ap = asinf(as_in);
            ep = fmaxf(ang - ap, 0.0f);
        }
    }
    if (blockIdx.x >= 1024 && blockIdx.x < 2048) {   // pure-dna blocks
        if (lane == 0) red[t >> 6] = ep;
        __syncthreads();
        if (t == 0) ent_partial[blockIdx.x - 1024] = red[0] + red[1] + red[2] + red[3];
    }
}

// ---- K2: batched fp8 MFMA GEMM (A·B^T), 128x128 tile, 8 waves, 32x64/wave.
//      R22: ZERO-LDS direct-from-L2 fragment loads. Four structurally
//      different staged variants (R17 1blk/CU, R18 pinned+spill, R20 phased
//      counted-vmcnt, R21 2blk/CU 4w/SIMD) ALL pinned at ~95us, MfmaUtil 21%
//      == mfma-floor/duration. Occupancy, scheduling, and reg budget are
//      each exonerated. The invariant: barrier-synced LDS staging of data
//      that is fully L2/L3-resident (f8 = 6 MB; FETCH 18 MB). learn_hip
//      common-mistake #7: staging L2-fit data is pure overhead.
//      Key identity: the K-interleaved layout makes each lane's MFMA frag
//      CONTIGUOUS in global: LDS slot s' of row r holds chunk s'^((r>>1)&3);
//      frag read slot q^((s>>1)&3) at row base+s (16-aligned base) => chunk
//      q exactly. So frag = global 16B at row*512 + si*64 + q*16. Per wave
//      instr: 16 rows x 64B contiguous, 64B-aligned -> clean L2 gather.
//      No LDS, no global_load_lds, NO BARRIERS: waves fully independent,
//      compiler pipelines loads across K-steps with counted vmcnt (the thing
//      it could never do across barrier drains).
//      NOTE (R20): 4 barriers/K-step phasing = +10% cost. NOTE (R19):
//      acc[8][4] spill +30us. NOTE (R18): launch_bounds min-waves VGPR pin
//      -> spill. NOTE (R15): per-block __threadfence() = writeback storm.
__global__ __launch_bounds__(512) void gemm_epi_kernel(
    const u8* __restrict__ f8, const float* __restrict__ times,
    const int* __restrict__ labels,
    const float* __restrict__ ls_p, const float* __restrict__ curv_p,
    float* __restrict__ rsum_e, float* __restrict__ rsum_t,
    float* __restrict__ csum_e, float* __restrict__ csum_t) {
    int z = blockIdx.z;                   // 0:(img,dna) 1:(img,txt) 2:(dna,txt)
    int pa = (z == 2) ? 1 : 0;
    int pb = (z == 0) ? 1 : 2;
    const u8* A  = f8 + (size_t)pa * (B_SZ * D_SZ);
    const u8* Bm = f8 + (size_t)pb * (B_SZ * D_SZ);

    int t = threadIdx.x;
    int rowBlk = blockIdx.y * 128;
    int colBlk = blockIdx.x * 128;
    int wave = t >> 6, lane = t & 63;
    int wr = wave >> 1;                   // row 32-group (0..3)
    int wc = wave & 1;                    // col 64-group (0..1)

    int q = lane >> 4, s = lane & 15;

    // Direct fragment pointers (see header derivation): lane (q,s) of frag
    // (ii|j) at K-step si reads 16B at row(base+s)*512 + si*64 + q*16.
    const u8* fA = A  + (size_t)(rowBlk + wr * 32 + s) * D_SZ + q * 16;
    const u8* fB = Bm + (size_t)(colBlk + wc * 64 + s) * D_SZ + q * 16;

    floatx4 acc[2][4];
    #pragma unroll
    for (int ii = 0; ii < 2; ++ii)
        #pragma unroll
        for (int j = 0; j < 4; ++j) acc[ii][j] = (floatx4){0.f, 0.f, 0.f, 0.f};

    #pragma unroll
    for (int si = 0; si < D_SZ / 64; ++si) {
        const int ko = si * 64;
        lng2 a0 = *(const lng2*)(fA + ko);            // rows +0..15
        lng2 a1 = *(const lng2*)(fA + 16 * D_SZ + ko);// rows +16..31
        lng2 b0 = *(const lng2*)(fB + ko);
        lng2 b1 = *(const lng2*)(fB + 16 * D_SZ + ko);
        lng2 b2 = *(const lng2*)(fB + 32 * D_SZ + ko);
        lng2 b3 = *(const lng2*)(fB + 48 * D_SZ + ko);
        FP8MFMA(acc[0][0], a0.x, b0.x); FP8MFMA(acc[0][1], a0.x, b1.x);
        FP8MFMA(acc[0][2], a0.x, b2.x); FP8MFMA(acc[0][3], a0.x, b3.x);
        FP8MFMA(acc[1][0], a1.x, b0.x); FP8MFMA(acc[1][1], a1.x, b1.x);
        FP8MFMA(acc[1][2], a1.x, b2.x); FP8MFMA(acc[1][3], a1.x, b3.x);
        FP8MFMA(acc[0][0], a0.y, b0.y); FP8MFMA(acc[0][1], a0.y, b1.y);
        FP8MFMA(acc[0][2], a0.y, b2.y); FP8MFMA(acc[0][3], a0.y, b3.y);
        FP8MFMA(acc[1][0], a1.y, b0.y); FP8MFMA(acc[1][1], a1.y, b1.y);
        FP8MFMA(acc[1][2], a1.y, b2.y); FP8MFMA(acc[1][3], a1.y, b3.y);
    }

    // ---- slim fused epilogue (verified R7-R21, unchanged) ----
    float ls = ls_p[0];
    float curv = curv_p[0];
    float rsc = rsqrtf(curv);
    float c2 = -ls * rsc;
    float c1 = c2 * 0.69314718f;
    float sh2p = SHIFT * 1.44269504f + c2;
    const float* tA = times + pa * B_SZ;
    const float* tB = times + pb * B_SZ;

    int rowbase = rowBlk + wr * 32;
    int colbase = colBlk + wc * 64;

    float tb[4]; int lb[4]; int mcol[4];
    #pragma unroll
    for (int j = 0; j < 4; ++j) {
        mcol[j] = colbase + j * 16 + s;
        tb[j] = tB[mcol[j]];
        lb[j] = labels[mcol[j]];
    }
    float colE[4] = {0.f, 0.f, 0.f, 0.f}, colT[4] = {0.f, 0.f, 0.f, 0.f};

    float* rsE = rsum_e + z * B_SZ;
    float* rsT = rsum_t + z * B_SZ;
    float* csE = csum_e + z * B_SZ;
    float* csT = csum_t + z * B_SZ;

    #pragma unroll
    for (int ii = 0; ii < 2; ++ii) {
        int nb = rowbase + ii * 16 + q * 4;   // this lane's 4 C rows
        float cta[4]; int la[4];
        #pragma unroll
        for (int r = 0; r < 4; ++r) { cta[r] = curv * tA[nb + r]; la[r] = labels[nb + r]; }
        float re[4] = {0.f, 0.f, 0.f, 0.f}, rt[4] = {0.f, 0.f, 0.f, 0.f};
        #pragma unroll
        for (int j = 0; j < 4; ++j) {
            floatx4 a = acc[ii][j];
            #pragma unroll
            for (int r = 0; r < 4; ++r) {
                float zc = fmaf(-curv, a[r], cta[r] * tb[j]);
                zc = fmaxf(zc, 1.0f + 1e-8f);
                float lz = __log2f(zc);
                float e = __builtin_amdgcn_exp2f(fmaf(c2, lz, sh2p));
                float tl = (la[r] == lb[j]) ? fmaf(c1, lz, c1) : 0.0f;
                re[r] += e; rt[r] += tl;
                colE[j] += e; colT[j] += tl;
            }
        }
        #pragma unroll
        for (int r = 0; r < 4; ++r) {
            #pragma unroll
            for (int m = 1; m <= 8; m <<= 1) {
                re[r] += __shfl_xor(re[r], m);
                rt[r] += __shfl_xor(rt[r], m);
            }
        }
        #pragma unroll
        for (int r = 0; r < 4; ++r) {
            if (s == r) {
                atomicAdd(&rsE[nb + r], re[r]);
                atomicAdd(&rsT[nb + r], rt[r]);
            }
        }
    }
    #pragma unroll
    for (int j = 0; j < 4; ++j) {
        colE[j] += __shfl_xor(colE[j], 16); colE[j] += __shfl_xor(colE[j], 32);
        colT[j] += __shfl_xor(colT[j], 16); colT[j] += __shfl_xor(colT[j], 32);
        if (q == 0) {
            atomicAdd(&csE[mcol[j]], colE[j]);
            atomicAdd(&csT[mcol[j]], colT[j]);
        }
    }
}

// ---- parallel finalize: 16 blocks, device-scope atomic accumulation; last
//      block (done counter) writes out. atomicAdd(p,0) read avoids stale L2. ----
__global__ __launch_bounds__(256) void finalize_kernel(
    const float* __restrict__ rsum_e, const float* __restrict__ rsum_t,
    const float* __restrict__ csum_e, const float* __restrict__ csum_t,
    const int* __restrict__ labels, const int* __restrict__ hist,
    const float* __restrict__ ent_partial,
    float* __restrict__ ce_acc, float* __restrict__ ent_acc,
    int* __restrict__ done, float* __restrict__ out) {
    __shared__ float red[4], red2[4];
    int b = blockIdx.x, tid = threadIdx.x;
    int n = b * 256 + tid;                 // covers 0..4095 exactly
    float Sn = (float)hist[labels[n]];
    float part = 0.0f;
    #pragma unroll
    for (int p = 0; p < 3; ++p) {
        part += Sn * (__logf(rsum_e[p * B_SZ + n]) - SHIFT) - rsum_t[p * B_SZ + n];
        part += Sn * (__logf(csum_e[p * B_SZ + n]) - SHIFT) - csum_t[p * B_SZ + n];
    }
    float ep = (b < 4) ? ent_partial[b * 256 + tid] : 0.0f;
    #pragma unroll
    for (int m = 1; m < 64; m <<= 1) {
        part += __shfl_xor(part, m);
        ep   += __shfl_xor(ep, m);
    }
    if ((tid & 63) == 0) { red[tid >> 6] = part; red2[tid >> 6] = ep; }
    __syncthreads();
    if (tid == 0) {
        atomicAdd(ce_acc, red[0] + red[1] + red[2] + red[3]);
        atomicAdd(ent_acc, red2[0] + red2[1] + red2[2] + red2[3]);
        __threadfence();
        if (atomicAdd(done, 1) == 15) {        // last of 16 blocks
            float ce = atomicAdd(ce_acc, 0.0f);    // coherent read
            float ent = atomicAdd(ent_acc, 0.0f);
            float contr = ce / (6.0f * (float)B_SZ);
            ent /= (float)B_SZ;
            out[0] = contr + 0.2f * ent;
            out[1] = contr;
            out[2] = ent;
        }
    }
}

// ---- workspace layout (bytes) ----
//   0       : fp8 feats (K-interleaved), 3*4096*512 = 6,291,456
//   6291456 : times[3][4096] f32   (49,152)
//   6340608 : rsum_e[12288 f]  \
//   6389760 : rsum_t           | zero region: 49155 floats
//   6438912 : csum_e           | (incl. ce_acc, ent_acc, done)
//   6488064 : csum_t           |
//   6537216 : ce_acc f32; 6537220: ent_acc f32; 6537224: done i32
//   6537228 : ent_partial[1024] f32 (every slot written by its dna block)
//   6541324 : hist[512] int (fully written by prep block 0)
extern "C" void kernel_launch(void* const* d_in, const int* in_sizes, int n_in,
                              void* d_out, int out_size, void* d_ws, size_t ws_size,
                              hipStream_t stream) {
    const float* img    = (const float*)d_in[0];
    const float* dna    = (const float*)d_in[1];
    const float* txt    = (const float*)d_in[2];
    const int*   labels = (const int*)d_in[3];
    const float* ls     = (const float*)d_in[4];
    const float* curv   = (const float*)d_in[5];

    char* ws = (char*)d_ws;
    u8*    f8     = (u8*)ws;
    float* times  = (float*)(ws + 6291456);
    float* rsum_e = (float*)(ws + 6340608);
    float* rsum_t = (float*)(ws + 6389760);
    float* csum_e = (float*)(ws + 6438912);
    float* csum_t = (float*)(ws + 6488064);
    float* ce_acc = (float*)(ws + 6537216);
    float* ent_acc= (float*)(ws + 6537220);
    int*   done   = (int*)  (ws + 6537224);
    float* ent_p  = (float*)(ws + 6537228);
    int*   hist   = (int*)  (ws + 6541324);

    prep_kernel<<<3072, 256, 0, stream>>>(img, dna, txt, curv, labels, hist,
                                          f8, times, rsum_e, ent_p);
    dim3 g(32, 32, 3);
    gemm_epi_kernel<<<g, 512, 0, stream>>>(f8, times, labels, ls, curv,
                                           rsum_e, rsum_t, csum_e, csum_t);
    finalize_kernel<<<16, 256, 0, stream>>>(rsum_e, rsum_t, csum_e, csum_t,
                                            labels, hist, ent_p,
                                            ce_acc, ent_acc, done, (float*)d_out);
}

// Round 6
// 171.375 us; speedup vs baseline: 1.4118x; 1.4118x over previous
//
#include <hip/hip_runtime.h>
#include <stdint.h>

#define B_SZ 4096
#define D_SZ 512
#define SHIFT 64.0f

typedef __attribute__((ext_vector_type(4))) float floatx4;
typedef __attribute__((ext_vector_type(2))) long lng2;
typedef unsigned char u8;
typedef unsigned int u32;

#define GLD_LDS16(gp, sp)                                                              \
    __builtin_amdgcn_global_load_lds(                                                  \
        (const __attribute__((address_space(1))) void*)(gp),                           \
        (__attribute__((address_space(3))) void*)(sp), 16, 0, 0)

#define FP8MFMA(accv, av, bv)                                                          \
    accv = __builtin_amdgcn_mfma_f32_16x16x32_fp8_fp8(av, bv, accv, 0, 0, 0)

// ---- K1: fp32->fp8(e4m3) convert (K-interleaved layout) + per-row time,
//      fused: histogram (block 0), accumulator zeroing, entailment partials.
//      K-perm: within each 64B K-window, 8B group (h,c) -> slot c*2+h; applied
//      to BOTH operands => Grammian unchanged. ----
__global__ __launch_bounds__(256) void prep_kernel(
    const float* __restrict__ img, const float* __restrict__ dna,
    const float* __restrict__ txt, const float* __restrict__ curv_p,
    const int* __restrict__ labels, int* __restrict__ hist,
    u8* __restrict__ f8, float* __restrict__ times,
    float* __restrict__ zero_f, float* __restrict__ ent_partial) {
    __shared__ int lhist[512];
    __shared__ float red[4];
    int t = threadIdx.x;
    int gid = blockIdx.x * 256 + t;
    if (gid < 49155) zero_f[gid] = 0.0f;    // rsum/csum + ce_acc/ent_acc/done

    if (blockIdx.x == 0) {                  // label histogram, single block
        lhist[t] = 0; lhist[t + 256] = 0;
        __syncthreads();
        for (int n = t; n < B_SZ; n += 256) atomicAdd(&lhist[labels[n]], 1);
        __syncthreads();
        hist[t] = lhist[t]; hist[t + 256] = lhist[t + 256];
    }

    int wave = gid >> 6;  // 0..12287
    int lane = t & 63;
    const float* src = (wave < B_SZ) ? img : (wave < 2 * B_SZ) ? dna : txt;
    int row = wave & (B_SZ - 1);
    const float* p = src + row * D_SZ + lane * 8;
    float4 v0 = *(const float4*)(p);
    float4 v1 = *(const float4*)(p + 4);
    float ss = v0.x*v0.x + v0.y*v0.y + v0.z*v0.z + v0.w*v0.w
             + v1.x*v1.x + v1.y*v1.y + v1.z*v1.z + v1.w*v1.w;
    u32 w0 = __builtin_amdgcn_cvt_pk_fp8_f32(v0.x, v0.y, 0, false);
    w0 = __builtin_amdgcn_cvt_pk_fp8_f32(v0.z, v0.w, w0, true);
    u32 w1 = __builtin_amdgcn_cvt_pk_fp8_f32(v1.x, v1.y, 0, false);
    w1 = __builtin_amdgcn_cvt_pk_fp8_f32(v1.z, v1.w, w1, true);
    uint2 pk; pk.x = w0; pk.y = w1;
    // lane = 8B group: window lane>>3, half (lane>>2)&1, chunk lane&3
    int gperm = (lane & 56) | ((lane & 3) << 1) | ((lane >> 2) & 1);
    *(uint2*)(f8 + (size_t)wave * D_SZ + gperm * 8) = pk;

    bool isdna = (wave >= B_SZ) && (wave < 2 * B_SZ);
    float dot = 0.0f, ssy = 0.0f;
    if (isdna) {                            // matching image row for entailment
        const float* y = img + row * D_SZ + lane * 8;
        float4 y0 = *(const float4*)y, y1 = *(const float4*)(y + 4);
        dot = v0.x*y0.x + v0.y*y0.y + v0.z*y0.z + v0.w*y0.w
            + v1.x*y1.x + v1.y*y1.y + v1.z*y1.z + v1.w*y1.w;
        ssy = y0.x*y0.x + y0.y*y0.y + y0.z*y0.z + y0.w*y0.w
            + y1.x*y1.x + y1.y*y1.y + y1.z*y1.z + y1.w*y1.w;
    }
    #pragma unroll
    for (int m = 1; m < 64; m <<= 1) {
        ss += __shfl_xor(ss, m);
        if (isdna) { dot += __shfl_xor(dot, m); ssy += __shfl_xor(ssy, m); }
    }
    float curv = curv_p[0];
    float ep = 0.0f;
    if (lane == 0) {
        float xt = sqrtf(1.0f / curv + ss);
        times[wave] = xt;
        if (isdna) {
            float yt = sqrtf(1.0f / curv + ssy);
            float nx = sqrtf(ss);
            float c = curv * (dot - xt * yt);                      // <= -1
            float numer = yt + c * xt;
            float denom = nx * sqrtf(fmaxf(c * c - 1.0f, 0.0f));
            float ai = numer / (denom + 1e-8f);
            ai = fminf(fmaxf(ai, -1.0f + 1e-8f), 1.0f - 1e-8f);
            float ang = acosf(ai);
            float as_in = 0.2f / (nx * sqrtf(curv) + 1e-6f);       // 2*min_radius
            as_in = fminf(fmaxf(as_in, -1.0f + 1e-6f), 1.0f - 1e-6f);
            float ap = asinf(as_in);
            ep = fmaxf(ang - ap, 0.0f);
        }
    }
    if (blockIdx.x >= 1024 && blockIdx.x < 2048) {   // pure-dna blocks
        if (lane == 0) red[t >> 6] = ep;
        __syncthreads();
        if (t == 0) ent_partial[blockIdx.x - 1024] = red[0] + red[1] + red[2] + red[3];
    }
}

// ---- K2: batched fp8 MFMA GEMM (A·B^T), 128x128 tile, 8 waves, 32x64/wave.
//      R23: R21 structure (equal-best, 95us gemm, no spill) + bijective
//      XCD-chunked tile remap.
//      Ledger: ~95us floor invariant across R17 (1blk/CU), R18 (spill+2x occ),
//      R20 (phased counted-vmcnt), R21 (2blk/CU 4w/SIMD). Exonerated:
//      occupancy, reg budget, phasing, bank conflicts (0), HBM (7%).
//      R22 (zero-LDS direct-L2 frags) = 168us, MfmaUtil 12: GEMM inner loops
//      NEED the LDS reuse (B frags re-read 4x); common-mistake #7 applies to
//      read-once data only. Staging is vindicated.
//      Untested-clean lever: L2 locality. Without swizzle, each XCD's
//      resident blocks touch all of f8 (6 MB > 4 MB per-XCD L2) -> staging
//      is serviced by L3 every K-step (384 MB chip-wide staging volume,
//      FETCH 18 MB => L3 not HBM). Remap: per z-slab (1024 blocks, %8==0),
//      XCD k owns 128 consecutive row-major tiles = 4 tile-rows ->
//      working set 0.25 MB (A) + 2 MB (B) = 2.25 MB < 4 MB L2.
//      NOTE (R22): direct-L2 frags = latency-bound, 12% MfmaUtil. NOTE (R20):
//      4 barriers/K-step phasing = +10% cost. NOTE (R19): acc[8][4] spill.
//      NOTE (R18): launch_bounds min-waves VGPR pin -> spill. NOTE (R15):
//      per-block __threadfence() = writeback storm.
__global__ __launch_bounds__(512, 4) void gemm_epi_kernel(
    const u8* __restrict__ f8, const float* __restrict__ times,
    const int* __restrict__ labels,
    const float* __restrict__ ls_p, const float* __restrict__ curv_p,
    float* __restrict__ rsum_e, float* __restrict__ rsum_t,
    float* __restrict__ csum_e, float* __restrict__ csum_t) {
    __shared__ u8 sA[2][128 * 64];    // 16 KB
    __shared__ u8 sB[2][128 * 64];    // 16 KB

    int z = blockIdx.z;                   // 0:(img,dna) 1:(img,txt) 2:(dna,txt)
    int pa = (z == 2) ? 1 : 0;
    int pb = (z == 0) ? 1 : 2;
    const u8* A  = f8 + (size_t)pa * (B_SZ * D_SZ);
    const u8* Bm = f8 + (size_t)pb * (B_SZ * D_SZ);

    // XCD-chunked bijective remap within the z-slab (1024 blocks, 1024%8==0):
    // dispatch-linear l -> tile tl; XCD (l&7) owns 128 consecutive tiles
    // (4 full tile-rows) -> per-XCD L2 working set 2.25 MB < 4 MB.
    int l  = blockIdx.y * 32 + blockIdx.x;
    int tl = (l & 7) * 128 + (l >> 3);
    int rowBlk = (tl >> 5) * 128;
    int colBlk = (tl & 31) * 128;

    int t = threadIdx.x;
    int wave = t >> 6, lane = t & 63;
    int wr = wave >> 1;                   // row 32-group (0..3)
    int wc = wave & 1;                    // col 64-group (0..1)

    // Staging: one 16B load per thread per tile per K-step.
    // LDS dest (linear lane scatter): thread t -> row t>>2, slot t&3.
    // Global source chunk = (t&3)^((t>>3)&3) => LDS[row][slot] holds global
    // chunk slot^((row>>1)&3) (involution; read applies the same XOR).
    int chunk = (t & 3) ^ ((t >> 3) & 3);
    const u8* gA = A  + (size_t)(rowBlk + (t >> 2)) * D_SZ + chunk * 16;
    const u8* gB = Bm + (size_t)(colBlk + (t >> 2)) * D_SZ + chunk * 16;

    int q = lane >> 4, s = lane & 15;
    // frag-read swizzle slot: q ^ ((row>>1)&3) == q ^ ((s>>1)&3) since all
    // row bases (wr*32, wc*64, ii*16, j*16) are 16-aligned.
    int slot16 = (q ^ ((s >> 1) & 3)) << 4;
    int aBase = (wr * 32 + s) * 64 + slot16;     // + ii*1024 per fragment
    int bBase = (wc * 64 + s) * 64 + slot16;     // + j*1024 per fragment

    floatx4 acc[2][4];
    #pragma unroll
    for (int ii = 0; ii < 2; ++ii)
        #pragma unroll
        for (int j = 0; j < 4; ++j) acc[ii][j] = (floatx4){0.f, 0.f, 0.f, 0.f};

    {   // prologue: stage K-step 0 into buffer 0 (2 loads per thread)
        GLD_LDS16(gA, &sA[0][wave * 1024]);
        GLD_LDS16(gB, &sB[0][wave * 1024]);
    }

    #pragma unroll
    for (int si = 0; si < D_SZ / 64; ++si) {
        const int cur = si & 1;
        // __syncthreads drains vmcnt(0)+lgkmcnt(0): stage(si) landed AND the
        // buffer about to be overwritten by the prefetch was fully read.
        __syncthreads();
        if (si < D_SZ / 64 - 1) {
            const int ko = (si + 1) * 64;
            GLD_LDS16(gA + ko, &sA[cur ^ 1][wave * 1024]);
            GLD_LDS16(gB + ko, &sB[cur ^ 1][wave * 1024]);
        }
        const u8* pA = &sA[cur][0];
        const u8* pB = &sB[cur][0];
        lng2 a0 = *(const lng2*)(pA + aBase);
        lng2 a1 = *(const lng2*)(pA + aBase + 1024);
        lng2 b0 = *(const lng2*)(pB + bBase);
        lng2 b1 = *(const lng2*)(pB + bBase + 1024);
        lng2 b2 = *(const lng2*)(pB + bBase + 2048);
        lng2 b3 = *(const lng2*)(pB + bBase + 3072);
        FP8MFMA(acc[0][0], a0.x, b0.x); FP8MFMA(acc[0][1], a0.x, b1.x);
        FP8MFMA(acc[0][2], a0.x, b2.x); FP8MFMA(acc[0][3], a0.x, b3.x);
        FP8MFMA(acc[1][0], a1.x, b0.x); FP8MFMA(acc[1][1], a1.x, b1.x);
        FP8MFMA(acc[1][2], a1.x, b2.x); FP8MFMA(acc[1][3], a1.x, b3.x);
        FP8MFMA(acc[0][0], a0.y, b0.y); FP8MFMA(acc[0][1], a0.y, b1.y);
        FP8MFMA(acc[0][2], a0.y, b2.y); FP8MFMA(acc[0][3], a0.y, b3.y);
        FP8MFMA(acc[1][0], a1.y, b0.y); FP8MFMA(acc[1][1], a1.y, b1.y);
        FP8MFMA(acc[1][2], a1.y, b2.y); FP8MFMA(acc[1][3], a1.y, b3.y);
    }

    // ---- slim fused epilogue (verified R7-R21, unchanged) ----
    float ls = ls_p[0];
    float curv = curv_p[0];
    float rsc = rsqrtf(curv);
    float c2 = -ls * rsc;
    float c1 = c2 * 0.69314718f;
    float sh2p = SHIFT * 1.44269504f + c2;
    const float* tA = times + pa * B_SZ;
    const float* tB = times + pb * B_SZ;

    int rowbase = rowBlk + wr * 32;
    int colbase = colBlk + wc * 64;

    float tb[4]; int lb[4]; int mcol[4];
    #pragma unroll
    for (int j = 0; j < 4; ++j) {
        mcol[j] = colbase + j * 16 + s;
        tb[j] = tB[mcol[j]];
        lb[j] = labels[mcol[j]];
    }
    float colE[4] = {0.f, 0.f, 0.f, 0.f}, colT[4] = {0.f, 0.f, 0.f, 0.f};

    float* rsE = rsum_e + z * B_SZ;
    float* rsT = rsum_t + z * B_SZ;
    float* csE = csum_e + z * B_SZ;
    float* csT = csum_t + z * B_SZ;

    #pragma unroll
    for (int ii = 0; ii < 2; ++ii) {
        int nb = rowbase + ii * 16 + q * 4;   // this lane's 4 C rows
        float cta[4]; int la[4];
        #pragma unroll
        for (int r = 0; r < 4; ++r) { cta[r] = curv * tA[nb + r]; la[r] = labels[nb + r]; }
        float re[4] = {0.f, 0.f, 0.f, 0.f}, rt[4] = {0.f, 0.f, 0.f, 0.f};
        #pragma unroll
        for (int j = 0; j < 4; ++j) {
            floatx4 a = acc[ii][j];
            #pragma unroll
            for (int r = 0; r < 4; ++r) {
                float zc = fmaf(-curv, a[r], cta[r] * tb[j]);
                zc = fmaxf(zc, 1.0f + 1e-8f);
                float lz = __log2f(zc);
                float e = __builtin_amdgcn_exp2f(fmaf(c2, lz, sh2p));
                float tl = (la[r] == lb[j]) ? fmaf(c1, lz, c1) : 0.0f;
                re[r] += e; rt[r] += tl;
                colE[j] += e; colT[j] += tl;
            }
        }
        #pragma unroll
        for (int r = 0; r < 4; ++r) {
            #pragma unroll
            for (int m = 1; m <= 8; m <<= 1) {
                re[r] += __shfl_xor(re[r], m);
                rt[r] += __shfl_xor(rt[r], m);
            }
        }
        #pragma unroll
        for (int r = 0; r < 4; ++r) {
            if (s == r) {
                atomicAdd(&rsE[nb + r], re[r]);
                atomicAdd(&rsT[nb + r], rt[r]);
            }
        }
    }
    #pragma unroll
    for (int j = 0; j < 4; ++j) {
        colE[j] += __shfl_xor(colE[j], 16); colE[j] += __shfl_xor(colE[j], 32);
        colT[j] += __shfl_xor(colT[j], 16); colT[j] += __shfl_xor(colT[j], 32);
        if (q == 0) {
            atomicAdd(&csE[mcol[j]], colE[j]);
            atomicAdd(&csT[mcol[j]], colT[j]);
        }
    }
}

// ---- parallel finalize: 16 blocks, device-scope atomic accumulation; last
//      block (done counter) writes out. atomicAdd(p,0) read avoids stale L2. ----
__global__ __launch_bounds__(256) void finalize_kernel(
    const float* __restrict__ rsum_e, const float* __restrict__ rsum_t,
    const float* __restrict__ csum_e, const float* __restrict__ csum_t,
    const int* __restrict__ labels, const int* __restrict__ hist,
    const float* __restrict__ ent_partial,
    float* __restrict__ ce_acc, float* __restrict__ ent_acc,
    int* __restrict__ done, float* __restrict__ out) {
    __shared__ float red[4], red2[4];
    int b = blockIdx.x, tid = threadIdx.x;
    int n = b * 256 + tid;                 // covers 0..4095 exactly
    float Sn = (float)hist[labels[n]];
    float part = 0.0f;
    #pragma unroll
    for (int p = 0; p < 3; ++p) {
        part += Sn * (__logf(rsum_e[p * B_SZ + n]) - SHIFT) - rsum_t[p * B_SZ + n];
        part += Sn * (__logf(csum_e[p * B_SZ + n]) - SHIFT) - csum_t[p * B_SZ + n];
    }
    float ep = (b < 4) ? ent_partial[b * 256 + tid] : 0.0f;
    #pragma unroll
    for (int m = 1; m < 64; m <<= 1) {
        part += __shfl_xor(part, m);
        ep   += __shfl_xor(ep, m);
    }
    if ((tid & 63) == 0) { red[tid >> 6] = part; red2[tid >> 6] = ep; }
    __syncthreads();
    if (tid == 0) {
        atomicAdd(ce_acc, red[0] + red[1] + red[2] + red[3]);
        atomicAdd(ent_acc, red2[0] + red2[1] + red2[2] + red2[3]);
        __threadfence();
        if (atomicAdd(done, 1) == 15) {        // last of 16 blocks
            float ce = atomicAdd(ce_acc, 0.0f);    // coherent read
            float ent = atomicAdd(ent_acc, 0.0f);
            float contr = ce / (6.0f * (float)B_SZ);
            ent /= (float)B_SZ;
            out[0] = contr + 0.2f * ent;
            out[1] = contr;
            out[2] = ent;
        }
    }
}

// ---- workspace layout (bytes) ----
//   0       : fp8 feats (K-interleaved), 3*4096*512 = 6,291,456
//   6291456 : times[3][4096] f32   (49,152)
//   6340608 : rsum_e[12288 f]  \
//   6389760 : rsum_t           | zero region: 49155 floats
//   6438912 : csum_e           | (incl. ce_acc, ent_acc, done)
//   6488064 : csum_t           |
//   6537216 : ce_acc f32; 6537220: ent_acc f32; 6537224: done i32
//   6537228 : ent_partial[1024] f32 (every slot written by its dna block)
//   6541324 : hist[512] int (fully written by prep block 0)
extern "C" void kernel_launch(void* const* d_in, const int* in_sizes, int n_in,
                              void* d_out, int out_size, void* d_ws, size_t ws_size,
                              hipStream_t stream) {
    const float* img    = (const float*)d_in[0];
    const float* dna    = (const float*)d_in[1];
    const float* txt    = (const float*)d_in[2];
    const int*   labels = (const int*)d_in[3];
    const float* ls     = (const float*)d_in[4];
    const float* curv   = (const float*)d_in[5];

    char* ws = (char*)d_ws;
    u8*    f8     = (u8*)ws;
    float* times  = (float*)(ws + 6291456);
    float* rsum_e = (float*)(ws + 6340608);
    float* rsum_t = (float*)(ws + 6389760);
    float* csum_e = (float*)(ws + 6438912);
    float* csum_t = (float*)(ws + 6488064);
    float* ce_acc = (float*)(ws + 6537216);
    float* ent_acc= (float*)(ws + 6537220);
    int*   done   = (int*)  (ws + 6537224);
    float* ent_p  = (float*)(ws + 6537228);
    int*   hist   = (int*)  (ws + 6541324);

    prep_kernel<<<3072, 256, 0, stream>>>(img, dna, txt, curv, labels, hist,
                                          f8, times, rsum_e, ent_p);
    dim3 g(32, 32, 3);
    gemm_epi_kernel<<<g, 512, 0, stream>>>(f8, times, labels, ls, curv,
                                           rsum_e, rsum_t, csum_e, csum_t);
    finalize_kernel<<<16, 256, 0, stream>>>(rsum_e, rsum_t, csum_e, csum_t,
                                            labels, hist, ent_p,
                                            ce_acc, ent_acc, done, (float*)d_out);
}

// Round 7
// 164.131 us; speedup vs baseline: 1.4741x; 1.0441x over previous
//
#include <hip/hip_runtime.h>
#include <stdint.h>

#define B_SZ 4096
#define D_SZ 512
#define SHIFT 64.0f

typedef __attribute__((ext_vector_type(4))) float floatx4;
typedef __attribute__((ext_vector_type(2))) long lng2;
typedef unsigned char u8;
typedef unsigned int u32;

#define GLD_LDS16(gp, sp)                                                              \
    __builtin_amdgcn_global_load_lds(                                                  \
        (const __attribute__((address_space(1))) void*)(gp),                           \
        (__attribute__((address_space(3))) void*)(sp), 16, 0, 0)

#define FP8MFMA(accv, av, bv)                                                          \
    accv = __builtin_amdgcn_mfma_f32_16x16x32_fp8_fp8(av, bv, accv, 0, 0, 0)

// ---- K1: fp32->fp8(e4m3) convert (K-interleaved layout) + per-row time,
//      fused: histogram (block 0), accumulator zeroing, entailment partials.
//      K-perm: within each 64B K-window, 8B group (h,c) -> slot c*2+h; applied
//      to BOTH operands => Grammian unchanged. ----
__global__ __launch_bounds__(256) void prep_kernel(
    const float* __restrict__ img, const float* __restrict__ dna,
    const float* __restrict__ txt, const float* __restrict__ curv_p,
    const int* __restrict__ labels, int* __restrict__ hist,
    u8* __restrict__ f8, float* __restrict__ times,
    float* __restrict__ zero_f, float* __restrict__ ent_partial) {
    __shared__ int lhist[512];
    __shared__ float red[4];
    int t = threadIdx.x;
    int gid = blockIdx.x * 256 + t;
    if (gid < 49155) zero_f[gid] = 0.0f;    // rsum/csum + ce_acc/ent_acc/done

    if (blockIdx.x == 0) {                  // label histogram, single block
        lhist[t] = 0; lhist[t + 256] = 0;
        __syncthreads();
        for (int n = t; n < B_SZ; n += 256) atomicAdd(&lhist[labels[n]], 1);
        __syncthreads();
        hist[t] = lhist[t]; hist[t + 256] = lhist[t + 256];
    }

    int wave = gid >> 6;  // 0..12287
    int lane = t & 63;
    const float* src = (wave < B_SZ) ? img : (wave < 2 * B_SZ) ? dna : txt;
    int row = wave & (B_SZ - 1);
    const float* p = src + row * D_SZ + lane * 8;
    float4 v0 = *(const float4*)(p);
    float4 v1 = *(const float4*)(p + 4);
    float ss = v0.x*v0.x + v0.y*v0.y + v0.z*v0.z + v0.w*v0.w
             + v1.x*v1.x + v1.y*v1.y + v1.z*v1.z + v1.w*v1.w;
    u32 w0 = __builtin_amdgcn_cvt_pk_fp8_f32(v0.x, v0.y, 0, false);
    w0 = __builtin_amdgcn_cvt_pk_fp8_f32(v0.z, v0.w, w0, true);
    u32 w1 = __builtin_amdgcn_cvt_pk_fp8_f32(v1.x, v1.y, 0, false);
    w1 = __builtin_amdgcn_cvt_pk_fp8_f32(v1.z, v1.w, w1, true);
    uint2 pk; pk.x = w0; pk.y = w1;
    // lane = 8B group: window lane>>3, half (lane>>2)&1, chunk lane&3
    int gperm = (lane & 56) | ((lane & 3) << 1) | ((lane >> 2) & 1);
    *(uint2*)(f8 + (size_t)wave * D_SZ + gperm * 8) = pk;

    bool isdna = (wave >= B_SZ) && (wave < 2 * B_SZ);
    float dot = 0.0f, ssy = 0.0f;
    if (isdna) {                            // matching image row for entailment
        const float* y = img + row * D_SZ + lane * 8;
        float4 y0 = *(const float4*)y, y1 = *(const float4*)(y + 4);
        dot = v0.x*y0.x + v0.y*y0.y + v0.z*y0.z + v0.w*y0.w
            + v1.x*y1.x + v1.y*y1.y + v1.z*y1.z + v1.w*y1.w;
        ssy = y0.x*y0.x + y0.y*y0.y + y0.z*y0.z + y0.w*y0.w
            + y1.x*y1.x + y1.y*y1.y + y1.z*y1.z + y1.w*y1.w;
    }
    #pragma unroll
    for (int m = 1; m < 64; m <<= 1) {
        ss += __shfl_xor(ss, m);
        if (isdna) { dot += __shfl_xor(dot, m); ssy += __shfl_xor(ssy, m); }
    }
    float curv = curv_p[0];
    float ep = 0.0f;
    if (lane == 0) {
        float xt = sqrtf(1.0f / curv + ss);
        times[wave] = xt;
        if (isdna) {
            float yt = sqrtf(1.0f / curv + ssy);
            float nx = sqrtf(ss);
            float c = curv * (dot - xt * yt);                      // <= -1
            float numer = yt + c * xt;
            float denom = nx * sqrtf(fmaxf(c * c - 1.0f, 0.0f));
            float ai = numer / (denom + 1e-8f);
            ai = fminf(fmaxf(ai, -1.0f + 1e-8f), 1.0f - 1e-8f);
            float ang = acosf(ai);
            float as_in = 0.2f / (nx * sqrtf(curv) + 1e-6f);       // 2*min_radius
            as_in = fminf(fmaxf(as_in, -1.0f + 1e-6f), 1.0f - 1e-6f);
            float ap = asinf(as_in);
            ep = fmaxf(ang - ap, 0.0f);
        }
    }
    if (blockIdx.x >= 1024 && blockIdx.x < 2048) {   // pure-dna blocks
        if (lane == 0) red[t >> 6] = ep;
        __syncthreads();
        if (t == 0) ent_partial[blockIdx.x - 1024] = red[0] + red[1] + red[2] + red[3];
    }
}

// ---- K2: batched fp8 MFMA GEMM (A·B^T), 128x128 tile, 8 waves, 32x64/wave.
//      R24: R21 structure with ONE change: triple-buffer + prefetch-distance-2
//      + counted vmcnt (no drain in-loop). Single phase, 1 barrier/K-step.
//      Rationale: VALUBusy(32%) includes MFMA issue on the gfx94x derived
//      formula -> real VALU ~11%; CU issues nothing ~65% of time at 40% occ.
//      Not throughput-bound (R18 absorbed 150 MB spill free), staging volume
//      irrelevant (R17 288MB == R21 384MB == 95us), L2 locality irrelevant
//      (R23 regressed). Shared invariant of every 95us variant: __syncthreads
//      = vmcnt(0) drain each K-step -> staging tail latency fully exposed,
//      every step, for every wave. R20's counted-vmcnt test was confounded by
//      its 4-barriers/step phasing; this is the clean single-variable run.
//      vmcnt ledger (2 GLD/wave/step): steady in-flight = stage(si)+stage(si+1)
//      = 4; oldest 2 = stage(si) -> vmcnt(2); si=7 -> vmcnt(0). Buffer safety:
//      stage(si+2) targets buf[(si-1)%3], whose reads completed before
//      barrier(si) (explicit lgkmcnt(0) pre-barrier).
//      Ledger: R22 direct-L2 frags = latency+redundancy-bound (168us).
//      R23 XCD remap regressed (103us). R20 4-phase = +10%. R19 acc[8][4]
//      spill. R18 min-waves VGPR pin spill. R15 per-block threadfence storm.
__global__ __launch_bounds__(512, 4) void gemm_epi_kernel(
    const u8* __restrict__ f8, const float* __restrict__ times,
    const int* __restrict__ labels,
    const float* __restrict__ ls_p, const float* __restrict__ curv_p,
    float* __restrict__ rsum_e, float* __restrict__ rsum_t,
    float* __restrict__ csum_e, float* __restrict__ csum_t) {
    __shared__ u8 sA[3][128 * 64];    // 24 KB
    __shared__ u8 sB[3][128 * 64];    // 24 KB -> 48 KB total, 2 blocks/CU

    int z = blockIdx.z;                   // 0:(img,dna) 1:(img,txt) 2:(dna,txt)
    int pa = (z == 2) ? 1 : 0;
    int pb = (z == 0) ? 1 : 2;
    const u8* A  = f8 + (size_t)pa * (B_SZ * D_SZ);
    const u8* Bm = f8 + (size_t)pb * (B_SZ * D_SZ);

    int t = threadIdx.x;
    int rowBlk = blockIdx.y * 128;
    int colBlk = blockIdx.x * 128;
    int wave = t >> 6, lane = t & 63;
    int wr = wave >> 1;                   // row 32-group (0..3)
    int wc = wave & 1;                    // col 64-group (0..1)

    // Staging: one 16B load per thread per tile per K-step.
    // LDS dest (linear lane scatter): thread t -> row t>>2, slot t&3.
    // Global source chunk = (t&3)^((t>>3)&3) => LDS[row][slot] holds global
    // chunk slot^((row>>1)&3) (involution; read applies the same XOR).
    int chunk = (t & 3) ^ ((t >> 3) & 3);
    const u8* gA = A  + (size_t)(rowBlk + (t >> 2)) * D_SZ + chunk * 16;
    const u8* gB = Bm + (size_t)(colBlk + (t >> 2)) * D_SZ + chunk * 16;

    int q = lane >> 4, s = lane & 15;
    // frag-read swizzle slot: q ^ ((row>>1)&3) == q ^ ((s>>1)&3) since all
    // row bases (wr*32, wc*64, ii*16, j*16) are 16-aligned.
    int slot16 = (q ^ ((s >> 1) & 3)) << 4;
    int aBase = (wr * 32 + s) * 64 + slot16;     // + ii*1024 per fragment
    int bBase = (wc * 64 + s) * 64 + slot16;     // + j*1024 per fragment

    floatx4 acc[2][4];
    #pragma unroll
    for (int ii = 0; ii < 2; ++ii)
        #pragma unroll
        for (int j = 0; j < 4; ++j) acc[ii][j] = (floatx4){0.f, 0.f, 0.f, 0.f};

    {   // prologue: stage K-steps 0,1 into buffers 0,1 (4 loads in flight;
        // issue order per stage: gA then gB, matching the in-loop order so
        // "oldest 2" == one full stage for vmcnt counting).
        GLD_LDS16(gA,      &sA[0][wave * 1024]);
        GLD_LDS16(gB,      &sB[0][wave * 1024]);
        GLD_LDS16(gA + 64, &sA[1][wave * 1024]);
        GLD_LDS16(gB + 64, &sB[1][wave * 1024]);
    }

    #pragma unroll
    for (int si = 0; si < D_SZ / 64; ++si) {
        const int cur = si % 3;
        // own prior-step ds_reads consumed before the barrier (buffer-reuse
        // safety for the distance-2 DMA target); then wait ONLY stage(si).
        asm volatile("s_waitcnt lgkmcnt(0)" ::: "memory");
        if (si < 7) { asm volatile("s_waitcnt vmcnt(2)" ::: "memory"); }
        else        { asm volatile("s_waitcnt vmcnt(0)" ::: "memory"); }
        asm volatile("s_barrier" ::: "memory");
        // prefetch distance 2: stage(si+2) into buf[(si+2)%3] (= buf[(si-1)%3],
        // fully read before barrier(si)). Loads stay in flight across the
        // next barrier -- no drain anywhere in the loop.
        if (si < 6) {
            const int nxb = (si + 2) % 3;
            const int ko  = (si + 2) * 64;
            GLD_LDS16(gA + ko, &sA[nxb][wave * 1024]);
            GLD_LDS16(gB + ko, &sB[nxb][wave * 1024]);
        }
        const u8* pA = &sA[cur][0];
        const u8* pB = &sB[cur][0];
        lng2 a0 = *(const lng2*)(pA + aBase);
        lng2 a1 = *(const lng2*)(pA + aBase + 1024);
        lng2 b0 = *(const lng2*)(pB + bBase);
        lng2 b1 = *(const lng2*)(pB + bBase + 1024);
        lng2 b2 = *(const lng2*)(pB + bBase + 2048);
        lng2 b3 = *(const lng2*)(pB + bBase + 3072);
        FP8MFMA(acc[0][0], a0.x, b0.x); FP8MFMA(acc[0][1], a0.x, b1.x);
        FP8MFMA(acc[0][2], a0.x, b2.x); FP8MFMA(acc[0][3], a0.x, b3.x);
        FP8MFMA(acc[1][0], a1.x, b0.x); FP8MFMA(acc[1][1], a1.x, b1.x);
        FP8MFMA(acc[1][2], a1.x, b2.x); FP8MFMA(acc[1][3], a1.x, b3.x);
        FP8MFMA(acc[0][0], a0.y, b0.y); FP8MFMA(acc[0][1], a0.y, b1.y);
        FP8MFMA(acc[0][2], a0.y, b2.y); FP8MFMA(acc[0][3], a0.y, b3.y);
        FP8MFMA(acc[1][0], a1.y, b0.y); FP8MFMA(acc[1][1], a1.y, b1.y);
        FP8MFMA(acc[1][2], a1.y, b2.y); FP8MFMA(acc[1][3], a1.y, b3.y);
    }

    // ---- slim fused epilogue (verified R7-R23, unchanged) ----
    float ls = ls_p[0];
    float curv = curv_p[0];
    float rsc = rsqrtf(curv);
    float c2 = -ls * rsc;
    float c1 = c2 * 0.69314718f;
    float sh2p = SHIFT * 1.44269504f + c2;
    const float* tA = times + pa * B_SZ;
    const float* tB = times + pb * B_SZ;

    int rowbase = rowBlk + wr * 32;
    int colbase = colBlk + wc * 64;

    float tb[4]; int lb[4]; int mcol[4];
    #pragma unroll
    for (int j = 0; j < 4; ++j) {
        mcol[j] = colbase + j * 16 + s;
        tb[j] = tB[mcol[j]];
        lb[j] = labels[mcol[j]];
    }
    float colE[4] = {0.f, 0.f, 0.f, 0.f}, colT[4] = {0.f, 0.f, 0.f, 0.f};

    float* rsE = rsum_e + z * B_SZ;
    float* rsT = rsum_t + z * B_SZ;
    float* csE = csum_e + z * B_SZ;
    float* csT = csum_t + z * B_SZ;

    #pragma unroll
    for (int ii = 0; ii < 2; ++ii) {
        int nb = rowbase + ii * 16 + q * 4;   // this lane's 4 C rows
        float cta[4]; int la[4];
        #pragma unroll
        for (int r = 0; r < 4; ++r) { cta[r] = curv * tA[nb + r]; la[r] = labels[nb + r]; }
        float re[4] = {0.f, 0.f, 0.f, 0.f}, rt[4] = {0.f, 0.f, 0.f, 0.f};
        #pragma unroll
        for (int j = 0; j < 4; ++j) {
            floatx4 a = acc[ii][j];
            #pragma unroll
            for (int r = 0; r < 4; ++r) {
                float zc = fmaf(-curv, a[r], cta[r] * tb[j]);
                zc = fmaxf(zc, 1.0f + 1e-8f);
                float lz = __log2f(zc);
                float e = __builtin_amdgcn_exp2f(fmaf(c2, lz, sh2p));
                float tl = (la[r] == lb[j]) ? fmaf(c1, lz, c1) : 0.0f;
                re[r] += e; rt[r] += tl;
                colE[j] += e; colT[j] += tl;
            }
        }
        #pragma unroll
        for (int r = 0; r < 4; ++r) {
            #pragma unroll
            for (int m = 1; m <= 8; m <<= 1) {
                re[r] += __shfl_xor(re[r], m);
                rt[r] += __shfl_xor(rt[r], m);
            }
        }
        #pragma unroll
        for (int r = 0; r < 4; ++r) {
            if (s == r) {
                atomicAdd(&rsE[nb + r], re[r]);
                atomicAdd(&rsT[nb + r], rt[r]);
            }
        }
    }
    #pragma unroll
    for (int j = 0; j < 4; ++j) {
        colE[j] += __shfl_xor(colE[j], 16); colE[j] += __shfl_xor(colE[j], 32);
        colT[j] += __shfl_xor(colT[j], 16); colT[j] += __shfl_xor(colT[j], 32);
        if (q == 0) {
            atomicAdd(&csE[mcol[j]], colE[j]);
            atomicAdd(&csT[mcol[j]], colT[j]);
        }
    }
}

// ---- parallel finalize: 16 blocks, device-scope atomic accumulation; last
//      block (done counter) writes out. atomicAdd(p,0) read avoids stale L2. ----
__global__ __launch_bounds__(256) void finalize_kernel(
    const float* __restrict__ rsum_e, const float* __restrict__ rsum_t,
    const float* __restrict__ csum_e, const float* __restrict__ csum_t,
    const int* __restrict__ labels, const int* __restrict__ hist,
    const float* __restrict__ ent_partial,
    float* __restrict__ ce_acc, float* __restrict__ ent_acc,
    int* __restrict__ done, float* __restrict__ out) {
    __shared__ float red[4], red2[4];
    int b = blockIdx.x, tid = threadIdx.x;
    int n = b * 256 + tid;                 // covers 0..4095 exactly
    float Sn = (float)hist[labels[n]];
    float part = 0.0f;
    #pragma unroll
    for (int p = 0; p < 3; ++p) {
        part += Sn * (__logf(rsum_e[p * B_SZ + n]) - SHIFT) - rsum_t[p * B_SZ + n];
        part += Sn * (__logf(csum_e[p * B_SZ + n]) - SHIFT) - csum_t[p * B_SZ + n];
    }
    float ep = (b < 4) ? ent_partial[b * 256 + tid] : 0.0f;
    #pragma unroll
    for (int m = 1; m < 64; m <<= 1) {
        part += __shfl_xor(part, m);
        ep   += __shfl_xor(ep, m);
    }
    if ((tid & 63) == 0) { red[tid >> 6] = part; red2[tid >> 6] = ep; }
    __syncthreads();
    if (tid == 0) {
        atomicAdd(ce_acc, red[0] + red[1] + red[2] + red[3]);
        atomicAdd(ent_acc, red2[0] + red2[1] + red2[2] + red2[3]);
        __threadfence();
        if (atomicAdd(done, 1) == 15) {        // last of 16 blocks
            float ce = atomicAdd(ce_acc, 0.0f);    // coherent read
            float ent = atomicAdd(ent_acc, 0.0f);
            float contr = ce / (6.0f * (float)B_SZ);
            ent /= (float)B_SZ;
            out[0] = contr + 0.2f * ent;
            out[1] = contr;
            out[2] = ent;
        }
    }
}

// ---- workspace layout (bytes) ----
//   0       : fp8 feats (K-interleaved), 3*4096*512 = 6,291,456
//   6291456 : times[3][4096] f32   (49,152)
//   6340608 : rsum_e[12288 f]  \
//   6389760 : rsum_t           | zero region: 49155 floats
//   6438912 : csum_e           | (incl. ce_acc, ent_acc, done)
//   6488064 : csum_t           |
//   6537216 : ce_acc f32; 6537220: ent_acc f32; 6537224: done i32
//   6537228 : ent_partial[1024] f32 (every slot written by its dna block)
//   6541324 : hist[512] int (fully written by prep block 0)
extern "C" void kernel_launch(void* const* d_in, const int* in_sizes, int n_in,
                              void* d_out, int out_size, void* d_ws, size_t ws_size,
                              hipStream_t stream) {
    const float* img    = (const float*)d_in[0];
    const float* dna    = (const float*)d_in[1];
    const float* txt    = (const float*)d_in[2];
    const int*   labels = (const int*)d_in[3];
    const float* ls     = (const float*)d_in[4];
    const float* curv   = (const float*)d_in[5];

    char* ws = (char*)d_ws;
    u8*    f8     = (u8*)ws;
    float* times  = (float*)(ws + 6291456);
    float* rsum_e = (float*)(ws + 6340608);
    float* rsum_t = (float*)(ws + 6389760);
    float* csum_e = (float*)(ws + 6438912);
    float* csum_t = (float*)(ws + 6488064);
    float* ce_acc = (float*)(ws + 6537216);
    float* ent_acc= (float*)(ws + 6537220);
    int*   done   = (int*)  (ws + 6537224);
    float* ent_p  = (float*)(ws + 6537228);
    int*   hist   = (int*)  (ws + 6541324);

    prep_kernel<<<3072, 256, 0, stream>>>(img, dna, txt, curv, labels, hist,
                                          f8, times, rsum_e, ent_p);
    dim3 g(32, 32, 3);
    gemm_epi_kernel<<<g, 512, 0, stream>>>(f8, times, labels, ls, curv,
                                           rsum_e, rsum_t, csum_e, csum_t);
    finalize_kernel<<<16, 256, 0, stream>>>(rsum_e, rsum_t, csum_e, csum_t,
                                            labels, hist, ent_p,
                                            ce_acc, ent_acc, done, (float*)d_out);
}